// Round 6
// baseline (98.954 us; speedup 1.0000x reference)
//
#include <hip/hip_runtime.h>
#include <hip/hip_bf16.h>

// ContrastiveLoss (SupCon-style), N=4096 rows, K=256 dim, TEMP=0.5.
// loss = mean over same-label off-diag pairs of [log(neg_i + e_ij) - t2_ij].
// e <= e^2 ~ 7.4, neg >= ~550 -> log(neg+e) = log n + e/n (2nd-order dropped,
// <=1e-4 rel [R7]). Stats symmetric (e_ij = e_ji) -> per-COLUMN sums:
// exsum, pexp, pt2, pcnt; neg = exsum - pexp;
// loss = S_j [c log n + pe/n - tt] / S_j c.
//
// R18: DIAGNOSTIC round. R17 post-mortem: cooperative launch never ran
// (absmax == ref loss 8.3125 -> out stayed 0; hipLaunchCooperativeKernel
// incompatible with harness graph capture / co-residency check, error
// unchecked). Structure floor = 3 kernels. Plateau 78.5-79.3 across R9-R16
// regardless of K2/K3 interior changes; the decision between "attack K2"
// and "declare floor" hinges on K2's true marginal cost, which the top-5
// counter table cannot show (five >=40us poison fills fill all slots).
// This round: R16-known-good source, negsum launched 3x (idempotent pure
// stores -> correctness unchanged). dur delta vs 78.5 = 2*(K2 + gap).
// ~98us -> K2 ~10us, attack K2 next. ~82us -> kernels negligible, revert
// and declare controllable floor.
//
// pk8 layout per 16-row tile (4096 B):
//   byte[u*1024 + quad*256 + r16*16 + h*8 + j] = fp8(norm8[r16][quad*8+(2u+h)*32+j])
// -> chunk (tile,u) = 1KB = one gll16/dwordx4 row; lane's 16B = c-steps
// {2u,2u+1} (k_local = quad*8 + j).
// C/D: col = lane&15, row = (lane>>4)*4 + reg  [learn_hip m89/m91; R3-R16
// validated end-to-end]. x8 scaling; acc = 64*sim -> t2 = acc * 2^-5 exact.
//
// ws: [0,1MB) pk8; [2MB,6MB) part[4][64][4096] f32; [6MB,+16B) acc[4]
//   (acc[0]=loss, acc[1]=cnt, acc[2]=ticket, acc[3]=pad).

#define N_ROWS 4096
#define K_DIM  256

typedef __attribute__((ext_vector_type(4))) float float4v;    // MFMA C/D
typedef __attribute__((ext_vector_type(4))) float f4;
typedef __attribute__((ext_vector_type(4))) int   int4v;
typedef __attribute__((ext_vector_type(2))) long  long2v;     // 2 x 8B frags

#define PK_OFF    0
#define PART_OFF  (2 * 1024 * 1024)
#define ACC_OFF   (PART_OFF + 4 * 64 * N_ROWS * 4)     // +4 MB

// async global->LDS, 16B/lane: dest = wave-uniform base + lane*16 [m97 path]
__device__ __forceinline__ void gll16(const void* g, void* l) {
    __builtin_amdgcn_global_load_lds(
        (const __attribute__((address_space(1))) unsigned int*)g,
        (__attribute__((address_space(3))) unsigned int*)l, 16, 0, 0);
}

// ---------------------------------------------------------------------------
// K1: block = one 16-row tile. Coalesced float4 loads -> LDS, per-row norms
// via 16-lane shuffle groups, x8-scaled fp8 pack, 16B/thread coalesced store.
__global__ void normalize_kernel(const float* __restrict__ emb,
                                 unsigned char* __restrict__ pk8,
                                 float* __restrict__ acc) {
    int tile = blockIdx.x, t = threadIdx.x;
    __shared__ float lds[16 * 256];
    __shared__ float sc[16];
    const f4* src = (const f4*)(emb + tile * 16 * 256);
    f4* dst4 = (f4*)lds;
    #pragma unroll
    for (int it = 0; it < 4; ++it) dst4[t + 256 * it] = src[t + 256 * it];
    __syncthreads();
    int wave = t >> 6, lane = t & 63;
    int row = wave * 4 + (lane >> 4);          // 4 rows per wave
    float s = 0.f;
    #pragma unroll
    for (int m = 0; m < 16; ++m) {
        float x = lds[row * 256 + (lane & 15) + 16 * m];
        s += x * x;
    }
    s += __shfl_xor(s, 1); s += __shfl_xor(s, 2);
    s += __shfl_xor(s, 4); s += __shfl_xor(s, 8);
    float scale = 1.0f / fmaxf(sqrtf(s), 1e-12f);
    if ((lane & 15) == 0) sc[row] = scale;
    __syncthreads();
    // pack 16 bytes: fixed (u, quad, r16) per thread; h,j sweep the 16B
    int u = t >> 6, quad = (t >> 4) & 3, r16 = t & 15;
    float s8 = sc[r16] * 8.0f;
    const float* lr = lds + r16 * 256;
    int4v wv;
    #pragma unroll
    for (int wi = 0; wi < 4; ++wi) {           // word wi = bytes 4wi..4wi+3
        int h  = wi >> 1;
        int j0 = (wi & 1) * 4;
        int kb = quad * 8 + (2 * u + h) * 32 + j0;
        float v0 = lr[kb + 0] * s8, v1 = lr[kb + 1] * s8;
        float v2 = lr[kb + 2] * s8, v3 = lr[kb + 3] * s8;
        int wd = __builtin_amdgcn_cvt_pk_fp8_f32(v0, v1, 0, 0);
        wd     = __builtin_amdgcn_cvt_pk_fp8_f32(v2, v3, wd, 1);
        wv[wi] = wd;
    }
    *(int4v*)(pk8 + tile * 4096 + t * 16) = wv;
    if (tile == 0 && t < 4) acc[t] = 0.0f;     // loss, cnt, ticket, pad
}

// ---------------------------------------------------------------------------
// K2: fp8 fused sim/exp/stats. Grid 1024 (XCD-swizzled) = 32x32 blocktiles of
// 128x128; 4 waves in 2x2, each a 64x64 subtile (4x4 MFMA frags).
// B-panel (32KB) staged via gll16 (async); A-frags loaded straight to VGPRs
// (16 dwordx4/wave, in flight alongside the gll16s). ONE barrier, then
// 16 ds_read_b128 + 128 MFMA per wave. 32KB LDS -> 3 blocks/CU.
__global__ __launch_bounds__(256, 3)
void negsum_kernel(const unsigned char* __restrict__ pk8,
                   const int* __restrict__ labels,
                   float* __restrict__ part) {
    __shared__ __align__(16) unsigned char Bs8[32768];   // 8 tiles x 4 chunks
    int t = threadIdx.x;
    int w = t >> 6, lane = t & 63;
    int lane16 = lane & 15, quad = lane >> 4;
    // XCD swizzle: 4 consecutive bi per XCD (A-panel stays L2-local)
    int xcd = blockIdx.x & 7, local = blockIdx.x >> 3;   // local 0..127
    int bi = xcd * 4 + (local >> 5);                     // 0..31
    int bj = local & 31;
    int wi = w >> 1, wj = w & 1;

    int ibase = bi * 128 + wi * 64;
    int jbase = bj * 128 + wj * 64;
    const char* pkb = (const char*)pk8;        // tile16 = 4KB, chunk = 1KB

    // ---- B-panel: 32 chunks of 1KB via async gll16 (8 per wave) ----
    #pragma unroll
    for (int u = 0; u < 8; ++u) {
        int c8 = w * 8 + u, tl = c8 >> 2, cs = c8 & 3;
        gll16(pkb + (((bj * 8 + tl) << 12) | (cs << 10)) + lane * 16,
              Bs8 + (c8 << 10));
    }
    // ---- A-frags straight to VGPRs (4 it-tiles x 4 cs, 16B each) ----
    long2v av[4][4];
    #pragma unroll
    for (int it = 0; it < 4; ++it)
        #pragma unroll
        for (int cs = 0; cs < 4; ++cs)
            av[it][cs] = *(const long2v*)(pkb
                + (((bi * 8 + wi * 4 + it) << 12) | (cs << 10)) + lane * 16);

    int labi[16], labj[4];
    #pragma unroll
    for (int it = 0; it < 4; ++it)
        #pragma unroll
        for (int r = 0; r < 4; ++r)
            labi[it * 4 + r] = labels[ibase + it * 16 + quad * 4 + r];
    #pragma unroll
    for (int jt = 0; jt < 4; ++jt)
        labj[jt] = labels[jbase + jt * 16 + lane16];

    float4v acc[4][4];
    #pragma unroll
    for (int a = 0; a < 4; ++a)
        #pragma unroll
        for (int b = 0; b < 4; ++b)
            acc[a][b] = (float4v){0.f, 0.f, 0.f, 0.f};

    __syncthreads();                           // drains gll16s (and A loads)

    #pragma unroll
    for (int cs = 0; cs < 4; ++cs) {
        long2v bv[4];
        #pragma unroll
        for (int jt = 0; jt < 4; ++jt)
            bv[jt] = *(const long2v*)(Bs8
                     + (((((wj * 4 + jt) << 2) | cs) << 10)) + lane * 16);
        #pragma unroll
        for (int h = 0; h < 2; ++h)
            #pragma unroll
            for (int it = 0; it < 4; ++it)
                #pragma unroll
                for (int jt = 0; jt < 4; ++jt)
                    acc[it][jt] = __builtin_amdgcn_mfma_f32_16x16x32_fp8_fp8(
                        av[it][cs][h], bv[jt][h], acc[it][jt], 0, 0, 0);
    }

    // epilogue: per-column stats (== per-row by symmetry); acc = 64*sim
    float ex[4] = {0,0,0,0}, pe[4] = {0,0,0,0};
    float tt[4] = {0,0,0,0}, pc[4] = {0,0,0,0};
    #pragma unroll
    for (int it = 0; it < 4; ++it) {
        #pragma unroll
        for (int jt = 0; jt < 4; ++jt) {
            int j = jbase + jt * 16 + lane16;
            #pragma unroll
            for (int r = 0; r < 4; ++r) {
                int i = ibase + it * 16 + quad * 4 + r;
                float t2 = acc[it][jt][r] * 0.03125f;   // 2*sim, exact pow2
                float e  = __expf(t2);
                bool keep = (i != j);
                bool same = (labi[it * 4 + r] == labj[jt]);
                ex[jt] += keep ? e : 0.0f;
                float m = (same && keep) ? 1.0f : 0.0f;
                pe[jt] = fmaf(m, e,  pe[jt]);
                tt[jt] = fmaf(m, t2, tt[jt]);
                pc[jt] += m;
            }
        }
    }
    int i64 = bi * 2 + wi;                     // this wave's 64-row chunk
    #pragma unroll
    for (int jt = 0; jt < 4; ++jt) {
        float v0 = ex[jt], v1 = pe[jt], v2 = tt[jt], v3 = pc[jt];
        v0 += __shfl_xor(v0, 16); v0 += __shfl_xor(v0, 32);
        v1 += __shfl_xor(v1, 16); v1 += __shfl_xor(v1, 32);
        v2 += __shfl_xor(v2, 16); v2 += __shfl_xor(v2, 32);
        v3 += __shfl_xor(v3, 16); v3 += __shfl_xor(v3, 32);
        if (quad == 0) {
            int col = jbase + jt * 16 + lane16;
            part[((0 * 64 + i64) << 12) + col] = v0;
            part[((1 * 64 + i64) << 12) + col] = v1;
            part[((2 * 64 + i64) << 12) + col] = v2;
            part[((3 * 64 + i64) << 12) + col] = v3;
        }
    }
}

// ---------------------------------------------------------------------------
// K3: slice-parallel rowreduce, coalesced mapping. Grid 128 x 256:
// block = 32 rows; thread (rl = t&31, sl = t>>5) sums 8 chunks of row
// (blk*32+rl) in slice sl -> each wave-load = 2 x 128B contiguous segments.
// Cross-slice reduce: shfl_xor(32) + 4x4x32 LDS pass. Ticket finalize.
__global__ void rowreduce_kernel(const float* __restrict__ part,
                                 float* __restrict__ acc,
                                 float* __restrict__ out) {
    int t = threadIdx.x;
    int rl = t & 31, sl = t >> 5;              // 8 slices x 32 rows
    int row = blockIdx.x * 32 + rl;
    float s[4];
    #pragma unroll
    for (int st = 0; st < 4; ++st) {
        float v = 0.f;
        #pragma unroll
        for (int c = 0; c < 8; ++c)
            v += part[((st * 64 + (sl * 8 + c)) << 12) + row];
        s[st] = v;
    }
    // combine the wave's two slices (lane ^ 32 = same row, other slice)
    #pragma unroll
    for (int st = 0; st < 4; ++st) s[st] += __shfl_xor(s[st], 32);
    __shared__ float sred[4][4][32];           // [wave][stat][row]
    int wave = t >> 6, lane = t & 63;
    if (lane < 32) {
        #pragma unroll
        for (int st = 0; st < 4; ++st) sred[wave][st][lane] = s[st];
    }
    __syncthreads();
    float lsum = 0.f, pcm = 0.f;
    if (t < 32) {
        float tot[4];
        #pragma unroll
        for (int st = 0; st < 4; ++st)
            tot[st] = sred[0][st][t] + sred[1][st][t]
                    + sred[2][st][t] + sred[3][st][t];
        if (tot[3] > 0.f) {
            float n = tot[0] - tot[1];         // neg = exsum - pexp
            lsum = tot[3] * logf(n) + tot[1] / n - tot[2];
            pcm  = tot[3];
        }
    }
    #pragma unroll
    for (int m = 1; m < 32; m <<= 1) {         // lanes 0..31 of wave 0
        lsum += __shfl_xor(lsum, m);
        pcm  += __shfl_xor(pcm,  m);
    }
    if (t == 0) {
        atomicAdd(&acc[0], lsum);
        atomicAdd(&acc[1], pcm);
        __threadfence();
        int ticket = atomicAdd((int*)(acc + 2), 1);
        if (ticket == 127) {
            float ls = atomicAdd(&acc[0], 0.0f);
            float cs = atomicAdd(&acc[1], 0.0f);
            out[0] = ls / cs;
        }
    }
}

// ---------------------------------------------------------------------------
extern "C" void kernel_launch(void* const* d_in, const int* in_sizes, int n_in,
                              void* d_out, int out_size, void* d_ws, size_t ws_size,
                              hipStream_t stream) {
    const float* emb    = (const float*)d_in[0];
    const int*   labels = (const int*)d_in[1];
    float* out = (float*)d_out;
    char*  ws  = (char*)d_ws;

    unsigned char* pk8  = (unsigned char*)(ws + PK_OFF);
    float*         part = (float*)(ws + PART_OFF);
    float*         acc  = (float*)(ws + ACC_OFF);

    normalize_kernel<<<N_ROWS / 16, 256, 0, stream>>>(emb, pk8, acc);
    // DIAGNOSTIC: K2 launched 3x (idempotent pure stores). dur delta vs
    // R16's 78.5us = 2*(K2 + launch gap). Revert to single launch next round.
    negsum_kernel<<<1024, 256, 0, stream>>>(pk8, labels, part);
    negsum_kernel<<<1024, 256, 0, stream>>>(pk8, labels, part);
    negsum_kernel<<<1024, 256, 0, stream>>>(pk8, labels, part);
    rowreduce_kernel<<<128, 256, 0, stream>>>(part, acc, out);
}

// Round 7
// 84.459 us; speedup vs baseline: 1.1716x; 1.1716x over previous
//
#include <hip/hip_runtime.h>
#include <hip/hip_bf16.h>

// ContrastiveLoss (SupCon-style), N=4096 rows, K=256 dim, TEMP=0.5.
// loss = mean over same-label off-diag pairs of [log(neg_i + e_ij) - t2_ij].
// e <= e^2 ~ 7.4, neg >= ~550 -> log(neg+e) = log n + e/n (2nd-order dropped,
// <=1e-4 rel [R7]). Stats symmetric -> per-COLUMN sums: exsum, pexp, pt2,
// pcnt; neg = exsum - pexp; loss = S_j [c log n + pe/n - tt] / S_j c.
//
// R19: attack K2 (R18 diagnostic: K2+gap = 10.2us, biggest controllable
// block). Two changes:
// (a) 512 blocks x 2 j-tiles (bj=2bjp,2bjp+1), A-frags/labi loaded once.
//     512 <= 768 slots (3 blocks/CU) -> ONE occupancy round (was 1.33 with
//     a 1/3-occupancy tail). Tile-1 staging issued after tile-0's MFMA
//     barrier -> flies under tile-0's epilogue VALU (latency hidden).
// (b) epilogue drops the keep=(i!=j) mask entirely: quantized e_ii is in
//     BOTH exsum and pexp -> cancels exactly in neg; pos-side diagonal is
//     the near-constant (exp(2), 2, 1) per column, subtracted once in K3.
//     Error ~1e-3 << 0.166 threshold (bf16 out step 0.0625). Saves the
//     compare+select+i-addr per element (16.7M elements).
//
// pk8 layout per 16-row tile (4096 B):
//   byte[u*1024 + quad*256 + r16*16 + h*8 + j] = fp8(norm8[r16][quad*8+(2u+h)*32+j])
// -> chunk (tile,u) = 1KB = one gll16/dwordx4 row; lane's 16B = c-steps
// {2u,2u+1} (k_local = quad*8 + j).
// C/D: col = lane&15, row = (lane>>4)*4 + reg  [learn_hip m89/m91; R3-R18
// validated end-to-end]. x8 scaling; acc = 64*sim -> t2 = acc * 2^-5 exact.
//
// ws: [0,1MB) pk8; [2MB,6MB) part[4][64][4096] f32; [6MB,+16B) acc[4]
//   (acc[0]=loss, acc[1]=cnt, acc[2]=ticket, acc[3]=pad).

#define N_ROWS 4096
#define K_DIM  256

typedef __attribute__((ext_vector_type(4))) float float4v;    // MFMA C/D
typedef __attribute__((ext_vector_type(4))) float f4;
typedef __attribute__((ext_vector_type(4))) int   int4v;
typedef __attribute__((ext_vector_type(2))) long  long2v;     // 2 x 8B frags

#define PK_OFF    0
#define PART_OFF  (2 * 1024 * 1024)
#define ACC_OFF   (PART_OFF + 4 * 64 * N_ROWS * 4)     // +4 MB

// async global->LDS, 16B/lane: dest = wave-uniform base + lane*16 [m97 path]
__device__ __forceinline__ void gll16(const void* g, void* l) {
    __builtin_amdgcn_global_load_lds(
        (const __attribute__((address_space(1))) unsigned int*)g,
        (__attribute__((address_space(3))) unsigned int*)l, 16, 0, 0);
}

// ---------------------------------------------------------------------------
// K1: block = one 16-row tile. Coalesced float4 loads -> LDS, per-row norms
// via 16-lane shuffle groups, x8-scaled fp8 pack, 16B/thread coalesced store.
__global__ void normalize_kernel(const float* __restrict__ emb,
                                 unsigned char* __restrict__ pk8,
                                 float* __restrict__ acc) {
    int tile = blockIdx.x, t = threadIdx.x;
    __shared__ float lds[16 * 256];
    __shared__ float sc[16];
    const f4* src = (const f4*)(emb + tile * 16 * 256);
    f4* dst4 = (f4*)lds;
    #pragma unroll
    for (int it = 0; it < 4; ++it) dst4[t + 256 * it] = src[t + 256 * it];
    __syncthreads();
    int wave = t >> 6, lane = t & 63;
    int row = wave * 4 + (lane >> 4);          // 4 rows per wave
    float s = 0.f;
    #pragma unroll
    for (int m = 0; m < 16; ++m) {
        float x = lds[row * 256 + (lane & 15) + 16 * m];
        s += x * x;
    }
    s += __shfl_xor(s, 1); s += __shfl_xor(s, 2);
    s += __shfl_xor(s, 4); s += __shfl_xor(s, 8);
    float scale = 1.0f / fmaxf(sqrtf(s), 1e-12f);
    if ((lane & 15) == 0) sc[row] = scale;
    __syncthreads();
    // pack 16 bytes: fixed (u, quad, r16) per thread; h,j sweep the 16B
    int u = t >> 6, quad = (t >> 4) & 3, r16 = t & 15;
    float s8 = sc[r16] * 8.0f;
    const float* lr = lds + r16 * 256;
    int4v wv;
    #pragma unroll
    for (int wi = 0; wi < 4; ++wi) {           // word wi = bytes 4wi..4wi+3
        int h  = wi >> 1;
        int j0 = (wi & 1) * 4;
        int kb = quad * 8 + (2 * u + h) * 32 + j0;
        float v0 = lr[kb + 0] * s8, v1 = lr[kb + 1] * s8;
        float v2 = lr[kb + 2] * s8, v3 = lr[kb + 3] * s8;
        int wd = __builtin_amdgcn_cvt_pk_fp8_f32(v0, v1, 0, 0);
        wd     = __builtin_amdgcn_cvt_pk_fp8_f32(v2, v3, wd, 1);
        wv[wi] = wd;
    }
    *(int4v*)(pk8 + tile * 4096 + t * 16) = wv;
    if (tile == 0 && t < 4) acc[t] = 0.0f;     // loss, cnt, ticket, pad
}

// ---------------------------------------------------------------------------
// K2: fp8 fused sim/exp/stats. Grid 512 (XCD-swizzled): block = 128 rows x
// TWO 128-col tiles (bj = 2bjp, 2bjp+1). 4 waves in 2x2, each 64x64/tile.
// B-panel (32KB) via gll16; A-frags once to VGPRs. Pipeline: MFMA0 ->
// barrier -> stage(tile1) || epilogue0+stores -> barrier -> MFMA1 ->
// epilogue1. Unmasked sums (diag corrected in K3).
__global__ __launch_bounds__(256, 3)
void negsum_kernel(const unsigned char* __restrict__ pk8,
                   const int* __restrict__ labels,
                   float* __restrict__ part) {
    __shared__ __align__(16) unsigned char Bs8[32768];   // 8 tiles x 4 chunks
    int t = threadIdx.x;
    int w = t >> 6, lane = t & 63;
    int lane16 = lane & 15, quad = lane >> 4;
    // XCD swizzle: 4 consecutive bi per XCD (A-panel stays L2-local)
    int xcd = blockIdx.x & 7, local = blockIdx.x >> 3;   // local 0..63
    int bi  = xcd * 4 + (local >> 4);                    // 0..31
    int bjp = local & 15;                                // 0..15
    int bj0 = bjp * 2;
    int wi = w >> 1, wj = w & 1;

    int ibase = bi * 128 + wi * 64;
    const char* pkb = (const char*)pk8;        // tile16 = 4KB, chunk = 1KB

    // ---- B-panel tile 0: 32 chunks of 1KB via async gll16 (8/wave) ----
    #pragma unroll
    for (int u = 0; u < 8; ++u) {
        int c8 = w * 8 + u, tl = c8 >> 2, cs = c8 & 3;
        gll16(pkb + (((bj0 * 8 + tl) << 12) | (cs << 10)) + lane * 16,
              Bs8 + (c8 << 10));
    }
    // ---- A-frags straight to VGPRs (4 it-tiles x 4 cs, 16B each) ----
    long2v av[4][4];
    #pragma unroll
    for (int it = 0; it < 4; ++it)
        #pragma unroll
        for (int cs = 0; cs < 4; ++cs)
            av[it][cs] = *(const long2v*)(pkb
                + (((bi * 8 + wi * 4 + it) << 12) | (cs << 10)) + lane * 16);

    int labi[16], labj0[4], labj1[4];
    #pragma unroll
    for (int it = 0; it < 4; ++it)
        #pragma unroll
        for (int r = 0; r < 4; ++r)
            labi[it * 4 + r] = labels[ibase + it * 16 + quad * 4 + r];
    #pragma unroll
    for (int jt = 0; jt < 4; ++jt) {
        labj0[jt] = labels[bj0 * 128       + wj * 64 + jt * 16 + lane16];
        labj1[jt] = labels[bj0 * 128 + 128 + wj * 64 + jt * 16 + lane16];
    }

    float4v acc[4][4];
    int i64 = bi * 2 + wi;                     // this wave's 64-row chunk

    // MFMA over the staged B-panel into acc (acc must be pre-zeroed)
    auto mfma_tile = [&]() {
        #pragma unroll
        for (int cs = 0; cs < 4; ++cs) {
            long2v bv[4];
            #pragma unroll
            for (int jt = 0; jt < 4; ++jt)
                bv[jt] = *(const long2v*)(Bs8
                         + (((((wj * 4 + jt) << 2) | cs) << 10)) + lane * 16);
            #pragma unroll
            for (int h = 0; h < 2; ++h)
                #pragma unroll
                for (int it = 0; it < 4; ++it)
                    #pragma unroll
                    for (int jt = 0; jt < 4; ++jt)
                        acc[it][jt] = __builtin_amdgcn_mfma_f32_16x16x32_fp8_fp8(
                            av[it][cs][h], bv[jt][h], acc[it][jt], 0, 0, 0);
        }
    };

    // epilogue: UNMASKED per-column stats (diag corrected in K3); acc=64*sim
    auto epi_tile = [&](int jbase, const int (&labjl)[4]) {
        float ex[4] = {0,0,0,0}, pe[4] = {0,0,0,0};
        float tt[4] = {0,0,0,0}, pc[4] = {0,0,0,0};
        #pragma unroll
        for (int it = 0; it < 4; ++it) {
            #pragma unroll
            for (int jt = 0; jt < 4; ++jt) {
                #pragma unroll
                for (int r = 0; r < 4; ++r) {
                    float t2 = acc[it][jt][r] * 0.03125f;   // 2*sim, exact
                    float e  = __expf(t2);
                    float m  = (labi[it * 4 + r] == labjl[jt]) ? 1.0f : 0.0f;
                    ex[jt] += e;
                    pe[jt] = fmaf(m, e,  pe[jt]);
                    tt[jt] = fmaf(m, t2, tt[jt]);
                    pc[jt] += m;
                }
            }
        }
        #pragma unroll
        for (int jt = 0; jt < 4; ++jt) {
            float v0 = ex[jt], v1 = pe[jt], v2 = tt[jt], v3 = pc[jt];
            v0 += __shfl_xor(v0, 16); v0 += __shfl_xor(v0, 32);
            v1 += __shfl_xor(v1, 16); v1 += __shfl_xor(v1, 32);
            v2 += __shfl_xor(v2, 16); v2 += __shfl_xor(v2, 32);
            v3 += __shfl_xor(v3, 16); v3 += __shfl_xor(v3, 32);
            if (quad == 0) {
                int col = jbase + jt * 16 + lane16;
                part[((0 * 64 + i64) << 12) + col] = v0;
                part[((1 * 64 + i64) << 12) + col] = v1;
                part[((2 * 64 + i64) << 12) + col] = v2;
                part[((3 * 64 + i64) << 12) + col] = v3;
            }
        }
    };

    // ---------------- tile 0 ----------------
    #pragma unroll
    for (int a = 0; a < 4; ++a)
        #pragma unroll
        for (int b = 0; b < 4; ++b)
            acc[a][b] = (float4v){0.f, 0.f, 0.f, 0.f};
    __syncthreads();                           // tile-0 staging complete
    mfma_tile();
    __syncthreads();                           // all waves done reading Bs8
    // issue tile-1 staging now; flies under epilogue-0 VALU
    #pragma unroll
    for (int u = 0; u < 8; ++u) {
        int c8 = w * 8 + u, tl = c8 >> 2, cs = c8 & 3;
        gll16(pkb + ((((bj0 + 1) * 8 + tl) << 12) | (cs << 10)) + lane * 16,
              Bs8 + (c8 << 10));
    }
    epi_tile(bj0 * 128 + wj * 64, labj0);
    // ---------------- tile 1 ----------------
    #pragma unroll
    for (int a = 0; a < 4; ++a)
        #pragma unroll
        for (int b = 0; b < 4; ++b)
            acc[a][b] = (float4v){0.f, 0.f, 0.f, 0.f};
    __syncthreads();                           // drains tile-1 gll16s
    mfma_tile();
    epi_tile(bj0 * 128 + 128 + wj * 64, labj1);
}

// ---------------------------------------------------------------------------
// K3: slice-parallel rowreduce, coalesced mapping (R16). Grid 128 x 256.
// NEW (R19): per-column diagonal correction — sums now include the diag
// elem; quantized e_ii cancels exactly in n = exsum - pexp; pos-side uses
// pe - exp(2), tt - 2, pc - 1 (error ~1e-3 << threshold).
__global__ void rowreduce_kernel(const float* __restrict__ part,
                                 float* __restrict__ acc,
                                 float* __restrict__ out) {
    int t = threadIdx.x;
    int rl = t & 31, sl = t >> 5;              // 8 slices x 32 rows
    int row = blockIdx.x * 32 + rl;
    float s[4];
    #pragma unroll
    for (int st = 0; st < 4; ++st) {
        float v = 0.f;
        #pragma unroll
        for (int c = 0; c < 8; ++c)
            v += part[((st * 64 + (sl * 8 + c)) << 12) + row];
        s[st] = v;
    }
    // combine the wave's two slices (lane ^ 32 = same row, other slice)
    #pragma unroll
    for (int st = 0; st < 4; ++st) s[st] += __shfl_xor(s[st], 32);
    __shared__ float sred[4][4][32];           // [wave][stat][row]
    int wave = t >> 6, lane = t & 63;
    if (lane < 32) {
        #pragma unroll
        for (int st = 0; st < 4; ++st) sred[wave][st][lane] = s[st];
    }
    __syncthreads();
    float lsum = 0.f, pcm = 0.f;
    if (t < 32) {
        float tot[4];
        #pragma unroll
        for (int st = 0; st < 4; ++st)
            tot[st] = sred[0][st][t] + sred[1][st][t]
                    + sred[2][st][t] + sred[3][st][t];
        float n   = tot[0] - tot[1];           // diag e_ii cancels exactly
        float pec = tot[1] - 7.3890560989f;    // pe  - exp(2)
        float ttc = tot[2] - 2.0f;             // tt  - 2
        float pcc = tot[3] - 1.0f;             // cnt - 1 (diag)
        if (pcc > 0.5f) {
            lsum = pcc * logf(n) + pec / n - ttc;
            pcm  = pcc;
        }
    }
    #pragma unroll
    for (int m = 1; m < 32; m <<= 1) {         // lanes 0..31 of wave 0
        lsum += __shfl_xor(lsum, m);
        pcm  += __shfl_xor(pcm,  m);
    }
    if (t == 0) {
        atomicAdd(&acc[0], lsum);
        atomicAdd(&acc[1], pcm);
        __threadfence();
        int ticket = atomicAdd((int*)(acc + 2), 1);
        if (ticket == 127) {
            float ls = atomicAdd(&acc[0], 0.0f);
            float cs = atomicAdd(&acc[1], 0.0f);
            out[0] = ls / cs;
        }
    }
}

// ---------------------------------------------------------------------------
extern "C" void kernel_launch(void* const* d_in, const int* in_sizes, int n_in,
                              void* d_out, int out_size, void* d_ws, size_t ws_size,
                              hipStream_t stream) {
    const float* emb    = (const float*)d_in[0];
    const int*   labels = (const int*)d_in[1];
    float* out = (float*)d_out;
    char*  ws  = (char*)d_ws;

    unsigned char* pk8  = (unsigned char*)(ws + PK_OFF);
    float*         part = (float*)(ws + PART_OFF);
    float*         acc  = (float*)(ws + ACC_OFF);

    normalize_kernel<<<N_ROWS / 16, 256, 0, stream>>>(emb, pk8, acc);
    negsum_kernel<<<512, 256, 0, stream>>>(pk8, labels, part);
    rowreduce_kernel<<<128, 256, 0, stream>>>(part, acc, out);
}

// Round 8
// 82.868 us; speedup vs baseline: 1.1941x; 1.0192x over previous
//
#include <hip/hip_runtime.h>
#include <hip/hip_bf16.h>

// ContrastiveLoss (SupCon-style), N=4096 rows, K=256 dim, TEMP=0.5.
// loss = mean over same-label off-diag pairs of [log(neg_i + e_ij) - t2_ij].
// e <= e^2 ~ 7.4, neg >= ~550 -> log(neg+e) = log n + e/n (2nd-order dropped,
// <=1e-4 rel [R7]). Stats symmetric -> per-COLUMN sums: exsum, pexp, pt2,
// pcnt; neg = exsum - pexp; loss = S_j [c log n + pe/n - tt] / S_j c.
//
// R20: R19 post-mortem: the 512-block/2-tile restructure (change a) cost
// +6us (2 blocks/CU vs 3, 3 barriers vs 1, serial tile chain) and drowned
// the epilogue slimming (change b, numerics validated: absmax 0.0).
// Third structural K2 regression -> R16 structure is a local optimum.
// R20 = R16 STRUCTURE VERBATIM (1024 blocks, XCD swizzle, 1 barrier,
// 3 blocks/CU) + ISOLATED subtractive epilogue slimming:
//   - no keep/(i!=j)/i-calc: diag e_ii cancels exactly in n=ex-pe;
//     pos-side diag consts (exp(2), 2, 1) subtracted once per row in K3.
//   - e = exp2f(acc * log2e/32): folds t2-mul into the exp2 constant;
//     tt accumulates RAW acc, scaled 2^-5 once per column at store.
//   12 -> 8 VALU/element on the dominant epilogue phase.
//
// pk8 layout per 16-row tile (4096 B):
//   byte[u*1024 + quad*256 + r16*16 + h*8 + j] = fp8(norm8[r16][quad*8+(2u+h)*32+j])
// -> chunk (tile,u) = 1KB = one gll16/dwordx4 row; lane's 16B = c-steps
// {2u,2u+1} (k_local = quad*8 + j).
// C/D: col = lane&15, row = (lane>>4)*4 + reg  [learn_hip m89/m91; R3-R19
// validated end-to-end]. x8 scaling; acc = 64*sim -> t2 = acc * 2^-5 exact.
//
// ws: [0,1MB) pk8; [2MB,6MB) part[4][64][4096] f32; [6MB,+16B) acc[4]
//   (acc[0]=loss, acc[1]=cnt, acc[2]=ticket, acc[3]=pad).

#define N_ROWS 4096
#define K_DIM  256

typedef __attribute__((ext_vector_type(4))) float float4v;    // MFMA C/D
typedef __attribute__((ext_vector_type(4))) float f4;
typedef __attribute__((ext_vector_type(4))) int   int4v;
typedef __attribute__((ext_vector_type(2))) long  long2v;     // 2 x 8B frags

#define PK_OFF    0
#define PART_OFF  (2 * 1024 * 1024)
#define ACC_OFF   (PART_OFF + 4 * 64 * N_ROWS * 4)     // +4 MB

// async global->LDS, 16B/lane: dest = wave-uniform base + lane*16 [m97 path]
__device__ __forceinline__ void gll16(const void* g, void* l) {
    __builtin_amdgcn_global_load_lds(
        (const __attribute__((address_space(1))) unsigned int*)g,
        (__attribute__((address_space(3))) unsigned int*)l, 16, 0, 0);
}

// ---------------------------------------------------------------------------
// K1: block = one 16-row tile. Coalesced float4 loads -> LDS, per-row norms
// via 16-lane shuffle groups, x8-scaled fp8 pack, 16B/thread coalesced store.
__global__ void normalize_kernel(const float* __restrict__ emb,
                                 unsigned char* __restrict__ pk8,
                                 float* __restrict__ acc) {
    int tile = blockIdx.x, t = threadIdx.x;
    __shared__ float lds[16 * 256];
    __shared__ float sc[16];
    const f4* src = (const f4*)(emb + tile * 16 * 256);
    f4* dst4 = (f4*)lds;
    #pragma unroll
    for (int it = 0; it < 4; ++it) dst4[t + 256 * it] = src[t + 256 * it];
    __syncthreads();
    int wave = t >> 6, lane = t & 63;
    int row = wave * 4 + (lane >> 4);          // 4 rows per wave
    float s = 0.f;
    #pragma unroll
    for (int m = 0; m < 16; ++m) {
        float x = lds[row * 256 + (lane & 15) + 16 * m];
        s += x * x;
    }
    s += __shfl_xor(s, 1); s += __shfl_xor(s, 2);
    s += __shfl_xor(s, 4); s += __shfl_xor(s, 8);
    float scale = 1.0f / fmaxf(sqrtf(s), 1e-12f);
    if ((lane & 15) == 0) sc[row] = scale;
    __syncthreads();
    // pack 16 bytes: fixed (u, quad, r16) per thread; h,j sweep the 16B
    int u = t >> 6, quad = (t >> 4) & 3, r16 = t & 15;
    float s8 = sc[r16] * 8.0f;
    const float* lr = lds + r16 * 256;
    int4v wv;
    #pragma unroll
    for (int wi = 0; wi < 4; ++wi) {           // word wi = bytes 4wi..4wi+3
        int h  = wi >> 1;
        int j0 = (wi & 1) * 4;
        int kb = quad * 8 + (2 * u + h) * 32 + j0;
        float v0 = lr[kb + 0] * s8, v1 = lr[kb + 1] * s8;
        float v2 = lr[kb + 2] * s8, v3 = lr[kb + 3] * s8;
        int wd = __builtin_amdgcn_cvt_pk_fp8_f32(v0, v1, 0, 0);
        wd     = __builtin_amdgcn_cvt_pk_fp8_f32(v2, v3, wd, 1);
        wv[wi] = wd;
    }
    *(int4v*)(pk8 + tile * 4096 + t * 16) = wv;
    if (tile == 0 && t < 4) acc[t] = 0.0f;     // loss, cnt, ticket, pad
}

// ---------------------------------------------------------------------------
// K2: fp8 fused sim/exp/stats. Grid 1024 (XCD-swizzled) = 32x32 blocktiles of
// 128x128; 4 waves in 2x2, each a 64x64 subtile (4x4 MFMA frags).
// B-panel (32KB) staged via gll16 (async); A-frags loaded straight to VGPRs
// (16 dwordx4/wave, in flight alongside the gll16s). ONE barrier, then
// 16 ds_read_b128 + 128 MFMA per wave. 32KB LDS -> 3 blocks/CU.
// Epilogue (R20): UNMASKED sums, exp2-folded constant, raw-acc tt.
__global__ __launch_bounds__(256, 3)
void negsum_kernel(const unsigned char* __restrict__ pk8,
                   const int* __restrict__ labels,
                   float* __restrict__ part) {
    __shared__ __align__(16) unsigned char Bs8[32768];   // 8 tiles x 4 chunks
    int t = threadIdx.x;
    int w = t >> 6, lane = t & 63;
    int lane16 = lane & 15, quad = lane >> 4;
    // XCD swizzle: 4 consecutive bi per XCD (A-panel stays L2-local)
    int xcd = blockIdx.x & 7, local = blockIdx.x >> 3;   // local 0..127
    int bi = xcd * 4 + (local >> 5);                     // 0..31
    int bj = local & 31;
    int wi = w >> 1, wj = w & 1;

    int ibase = bi * 128 + wi * 64;
    int jbase = bj * 128 + wj * 64;
    const char* pkb = (const char*)pk8;        // tile16 = 4KB, chunk = 1KB

    // ---- B-panel: 32 chunks of 1KB via async gll16 (8 per wave) ----
    #pragma unroll
    for (int u = 0; u < 8; ++u) {
        int c8 = w * 8 + u, tl = c8 >> 2, cs = c8 & 3;
        gll16(pkb + (((bj * 8 + tl) << 12) | (cs << 10)) + lane * 16,
              Bs8 + (c8 << 10));
    }
    // ---- A-frags straight to VGPRs (4 it-tiles x 4 cs, 16B each) ----
    long2v av[4][4];
    #pragma unroll
    for (int it = 0; it < 4; ++it)
        #pragma unroll
        for (int cs = 0; cs < 4; ++cs)
            av[it][cs] = *(const long2v*)(pkb
                + (((bi * 8 + wi * 4 + it) << 12) | (cs << 10)) + lane * 16);

    int labi[16], labj[4];
    #pragma unroll
    for (int it = 0; it < 4; ++it)
        #pragma unroll
        for (int r = 0; r < 4; ++r)
            labi[it * 4 + r] = labels[ibase + it * 16 + quad * 4 + r];
    #pragma unroll
    for (int jt = 0; jt < 4; ++jt)
        labj[jt] = labels[jbase + jt * 16 + lane16];

    float4v acc[4][4];
    #pragma unroll
    for (int a = 0; a < 4; ++a)
        #pragma unroll
        for (int b = 0; b < 4; ++b)
            acc[a][b] = (float4v){0.f, 0.f, 0.f, 0.f};

    __syncthreads();                           // drains gll16s (and A loads)

    #pragma unroll
    for (int cs = 0; cs < 4; ++cs) {
        long2v bv[4];
        #pragma unroll
        for (int jt = 0; jt < 4; ++jt)
            bv[jt] = *(const long2v*)(Bs8
                     + (((((wj * 4 + jt) << 2) | cs) << 10)) + lane * 16);
        #pragma unroll
        for (int h = 0; h < 2; ++h)
            #pragma unroll
            for (int it = 0; it < 4; ++it)
                #pragma unroll
                for (int jt = 0; jt < 4; ++jt)
                    acc[it][jt] = __builtin_amdgcn_mfma_f32_16x16x32_fp8_fp8(
                        av[it][cs][h], bv[jt][h], acc[it][jt], 0, 0, 0);
    }

    // epilogue (R20): unmasked per-column stats; acc = 64*sim.
    // e = exp(acc/32) = exp2(acc * log2e/32); tt accumulates RAW acc.
    float ex[4] = {0,0,0,0}, pe[4] = {0,0,0,0};
    float tt[4] = {0,0,0,0}, pc[4] = {0,0,0,0};
    #pragma unroll
    for (int it = 0; it < 4; ++it) {
        #pragma unroll
        for (int jt = 0; jt < 4; ++jt) {
            #pragma unroll
            for (int r = 0; r < 4; ++r) {
                float a = acc[it][jt][r];
                float e = exp2f(a * 0.04508422f);       // log2(e)/32
                float m = (labi[it * 4 + r] == labj[jt]) ? 1.0f : 0.0f;
                ex[jt] += e;
                pe[jt] = fmaf(m, e, pe[jt]);
                tt[jt] = fmaf(m, a, tt[jt]);            // raw; scaled at store
                pc[jt] += m;
            }
        }
    }
    int i64 = bi * 2 + wi;                     // this wave's 64-row chunk
    #pragma unroll
    for (int jt = 0; jt < 4; ++jt) {
        float v0 = ex[jt], v1 = pe[jt], v2 = tt[jt], v3 = pc[jt];
        v0 += __shfl_xor(v0, 16); v0 += __shfl_xor(v0, 32);
        v1 += __shfl_xor(v1, 16); v1 += __shfl_xor(v1, 32);
        v2 += __shfl_xor(v2, 16); v2 += __shfl_xor(v2, 32);
        v3 += __shfl_xor(v3, 16); v3 += __shfl_xor(v3, 32);
        if (quad == 0) {
            int col = jbase + jt * 16 + lane16;
            part[((0 * 64 + i64) << 12) + col] = v0;
            part[((1 * 64 + i64) << 12) + col] = v1;
            part[((2 * 64 + i64) << 12) + col] = v2 * 0.03125f;  // -> t2 sum
            part[((3 * 64 + i64) << 12) + col] = v3;
        }
    }
}

// ---------------------------------------------------------------------------
// K3: slice-parallel rowreduce, coalesced mapping (R16). Grid 128 x 256.
// Diag correction (validated R19): sums include the diag elem; quantized
// e_ii cancels exactly in n = exsum - pexp; pos-side uses pe - exp(2),
// tt - 2, pc - 1 (error ~1e-3 << threshold).
__global__ void rowreduce_kernel(const float* __restrict__ part,
                                 float* __restrict__ acc,
                                 float* __restrict__ out) {
    int t = threadIdx.x;
    int rl = t & 31, sl = t >> 5;              // 8 slices x 32 rows
    int row = blockIdx.x * 32 + rl;
    float s[4];
    #pragma unroll
    for (int st = 0; st < 4; ++st) {
        float v = 0.f;
        #pragma unroll
        for (int c = 0; c < 8; ++c)
            v += part[((st * 64 + (sl * 8 + c)) << 12) + row];
        s[st] = v;
    }
    // combine the wave's two slices (lane ^ 32 = same row, other slice)
    #pragma unroll
    for (int st = 0; st < 4; ++st) s[st] += __shfl_xor(s[st], 32);
    __shared__ float sred[4][4][32];           // [wave][stat][row]
    int wave = t >> 6, lane = t & 63;
    if (lane < 32) {
        #pragma unroll
        for (int st = 0; st < 4; ++st) sred[wave][st][lane] = s[st];
    }
    __syncthreads();
    float lsum = 0.f, pcm = 0.f;
    if (t < 32) {
        float tot[4];
        #pragma unroll
        for (int st = 0; st < 4; ++st)
            tot[st] = sred[0][st][t] + sred[1][st][t]
                    + sred[2][st][t] + sred[3][st][t];
        float n   = tot[0] - tot[1];           // diag e_ii cancels exactly
        float pec = tot[1] - 7.3890560989f;    // pe  - exp(2)
        float ttc = tot[2] - 2.0f;             // tt  - 2
        float pcc = tot[3] - 1.0f;             // cnt - 1 (diag)
        if (pcc > 0.5f) {
            lsum = pcc * logf(n) + pec / n - ttc;
            pcm  = pcc;
        }
    }
    #pragma unroll
    for (int m = 1; m < 32; m <<= 1) {         // lanes 0..31 of wave 0
        lsum += __shfl_xor(lsum, m);
        pcm  += __shfl_xor(pcm,  m);
    }
    if (t == 0) {
        atomicAdd(&acc[0], lsum);
        atomicAdd(&acc[1], pcm);
        __threadfence();
        int ticket = atomicAdd((int*)(acc + 2), 1);
        if (ticket == 127) {
            float ls = atomicAdd(&acc[0], 0.0f);
            float cs = atomicAdd(&acc[1], 0.0f);
            out[0] = ls / cs;
        }
    }
}

// ---------------------------------------------------------------------------
extern "C" void kernel_launch(void* const* d_in, const int* in_sizes, int n_in,
                              void* d_out, int out_size, void* d_ws, size_t ws_size,
                              hipStream_t stream) {
    const float* emb    = (const float*)d_in[0];
    const int*   labels = (const int*)d_in[1];
    float* out = (float*)d_out;
    char*  ws  = (char*)d_ws;

    unsigned char* pk8  = (unsigned char*)(ws + PK_OFF);
    float*         part = (float*)(ws + PART_OFF);
    float*         acc  = (float*)(ws + ACC_OFF);

    normalize_kernel<<<N_ROWS / 16, 256, 0, stream>>>(emb, pk8, acc);
    negsum_kernel<<<1024, 256, 0, stream>>>(pk8, labels, part);
    rowreduce_kernel<<<128, 256, 0, stream>>>(part, acc, out);
}

// Round 9
// 77.787 us; speedup vs baseline: 1.2721x; 1.0653x over previous
//
#include <hip/hip_runtime.h>
#include <hip/hip_bf16.h>

// ContrastiveLoss (SupCon-style), N=4096 rows, K=256 dim, TEMP=0.5.
// loss = mean over same-label off-diag pairs of [log(neg_i + e_ij) - t2_ij].
// e <= e^2 ~ 7.4, neg >= ~550 -> log(neg+e) = log n + e/n (2nd-order dropped,
// <=1e-4 rel [R7]). Stats symmetric -> per-COLUMN sums: exsum, pexp, pt2,
// pcnt; neg = exsum - pexp; loss = S_j [c log n + pe/n - tt] / S_j c.
//
// R21: R20 post-mortem: +4.4us came from libm exp2f (non-native: denormal/
// range fixup per call, 16.7M calls) -- NOT from the mask removal (strictly
// fewer ops, absmax 0.0 in R19+R20). R21 = R16 structure verbatim +
// unmasked epilogue + NATIVE exp2 via __builtin_amdgcn_exp2f (raw
// v_exp_f32, same unit __expf uses). Per-element epilogue 12 -> 8 VALU.
// K3 keeps the validated diag correction (e_ii cancels exactly in n;
// pos-side subtracts exp(2), 2, 1 per row).
//
// pk8 layout per 16-row tile (4096 B):
//   byte[u*1024 + quad*256 + r16*16 + h*8 + j] = fp8(norm8[r16][quad*8+(2u+h)*32+j])
// -> chunk (tile,u) = 1KB = one gll16/dwordx4 row; lane's 16B = c-steps
// {2u,2u+1} (k_local = quad*8 + j).
// C/D: col = lane&15, row = (lane>>4)*4 + reg  [learn_hip m89/m91; R3-R20
// validated end-to-end]. x8 scaling; acc = 64*sim -> t2 = acc * 2^-5 exact.
//
// ws: [0,1MB) pk8; [2MB,6MB) part[4][64][4096] f32; [6MB,+16B) acc[4]
//   (acc[0]=loss, acc[1]=cnt, acc[2]=ticket, acc[3]=pad).

#define N_ROWS 4096
#define K_DIM  256

typedef __attribute__((ext_vector_type(4))) float float4v;    // MFMA C/D
typedef __attribute__((ext_vector_type(4))) float f4;
typedef __attribute__((ext_vector_type(4))) int   int4v;
typedef __attribute__((ext_vector_type(2))) long  long2v;     // 2 x 8B frags

#define PK_OFF    0
#define PART_OFF  (2 * 1024 * 1024)
#define ACC_OFF   (PART_OFF + 4 * 64 * N_ROWS * 4)     // +4 MB

// async global->LDS, 16B/lane: dest = wave-uniform base + lane*16 [m97 path]
__device__ __forceinline__ void gll16(const void* g, void* l) {
    __builtin_amdgcn_global_load_lds(
        (const __attribute__((address_space(1))) unsigned int*)g,
        (__attribute__((address_space(3))) unsigned int*)l, 16, 0, 0);
}

// ---------------------------------------------------------------------------
// K1: block = one 16-row tile. Coalesced float4 loads -> LDS, per-row norms
// via 16-lane shuffle groups, x8-scaled fp8 pack, 16B/thread coalesced store.
__global__ void normalize_kernel(const float* __restrict__ emb,
                                 unsigned char* __restrict__ pk8,
                                 float* __restrict__ acc) {
    int tile = blockIdx.x, t = threadIdx.x;
    __shared__ float lds[16 * 256];
    __shared__ float sc[16];
    const f4* src = (const f4*)(emb + tile * 16 * 256);
    f4* dst4 = (f4*)lds;
    #pragma unroll
    for (int it = 0; it < 4; ++it) dst4[t + 256 * it] = src[t + 256 * it];
    __syncthreads();
    int wave = t >> 6, lane = t & 63;
    int row = wave * 4 + (lane >> 4);          // 4 rows per wave
    float s = 0.f;
    #pragma unroll
    for (int m = 0; m < 16; ++m) {
        float x = lds[row * 256 + (lane & 15) + 16 * m];
        s += x * x;
    }
    s += __shfl_xor(s, 1); s += __shfl_xor(s, 2);
    s += __shfl_xor(s, 4); s += __shfl_xor(s, 8);
    float scale = 1.0f / fmaxf(sqrtf(s), 1e-12f);
    if ((lane & 15) == 0) sc[row] = scale;
    __syncthreads();
    // pack 16 bytes: fixed (u, quad, r16) per thread; h,j sweep the 16B
    int u = t >> 6, quad = (t >> 4) & 3, r16 = t & 15;
    float s8 = sc[r16] * 8.0f;
    const float* lr = lds + r16 * 256;
    int4v wv;
    #pragma unroll
    for (int wi = 0; wi < 4; ++wi) {           // word wi = bytes 4wi..4wi+3
        int h  = wi >> 1;
        int j0 = (wi & 1) * 4;
        int kb = quad * 8 + (2 * u + h) * 32 + j0;
        float v0 = lr[kb + 0] * s8, v1 = lr[kb + 1] * s8;
        float v2 = lr[kb + 2] * s8, v3 = lr[kb + 3] * s8;
        int wd = __builtin_amdgcn_cvt_pk_fp8_f32(v0, v1, 0, 0);
        wd     = __builtin_amdgcn_cvt_pk_fp8_f32(v2, v3, wd, 1);
        wv[wi] = wd;
    }
    *(int4v*)(pk8 + tile * 4096 + t * 16) = wv;
    if (tile == 0 && t < 4) acc[t] = 0.0f;     // loss, cnt, ticket, pad
}

// ---------------------------------------------------------------------------
// K2: fp8 fused sim/exp/stats. Grid 1024 (XCD-swizzled) = 32x32 blocktiles of
// 128x128; 4 waves in 2x2, each a 64x64 subtile (4x4 MFMA frags).
// B-panel (32KB) staged via gll16 (async); A-frags loaded straight to VGPRs
// (16 dwordx4/wave, in flight alongside the gll16s). ONE barrier, then
// 16 ds_read_b128 + 128 MFMA per wave. 32KB LDS -> 3 blocks/CU.
// Epilogue (R21): UNMASKED sums, NATIVE exp2 (v_exp_f32), raw-acc tt.
__global__ __launch_bounds__(256, 3)
void negsum_kernel(const unsigned char* __restrict__ pk8,
                   const int* __restrict__ labels,
                   float* __restrict__ part) {
    __shared__ __align__(16) unsigned char Bs8[32768];   // 8 tiles x 4 chunks
    int t = threadIdx.x;
    int w = t >> 6, lane = t & 63;
    int lane16 = lane & 15, quad = lane >> 4;
    // XCD swizzle: 4 consecutive bi per XCD (A-panel stays L2-local)
    int xcd = blockIdx.x & 7, local = blockIdx.x >> 3;   // local 0..127
    int bi = xcd * 4 + (local >> 5);                     // 0..31
    int bj = local & 31;
    int wi = w >> 1, wj = w & 1;

    int ibase = bi * 128 + wi * 64;
    int jbase = bj * 128 + wj * 64;
    const char* pkb = (const char*)pk8;        // tile16 = 4KB, chunk = 1KB

    // ---- B-panel: 32 chunks of 1KB via async gll16 (8 per wave) ----
    #pragma unroll
    for (int u = 0; u < 8; ++u) {
        int c8 = w * 8 + u, tl = c8 >> 2, cs = c8 & 3;
        gll16(pkb + (((bj * 8 + tl) << 12) | (cs << 10)) + lane * 16,
              Bs8 + (c8 << 10));
    }
    // ---- A-frags straight to VGPRs (4 it-tiles x 4 cs, 16B each) ----
    long2v av[4][4];
    #pragma unroll
    for (int it = 0; it < 4; ++it)
        #pragma unroll
        for (int cs = 0; cs < 4; ++cs)
            av[it][cs] = *(const long2v*)(pkb
                + (((bi * 8 + wi * 4 + it) << 12) | (cs << 10)) + lane * 16);

    int labi[16], labj[4];
    #pragma unroll
    for (int it = 0; it < 4; ++it)
        #pragma unroll
        for (int r = 0; r < 4; ++r)
            labi[it * 4 + r] = labels[ibase + it * 16 + quad * 4 + r];
    #pragma unroll
    for (int jt = 0; jt < 4; ++jt)
        labj[jt] = labels[jbase + jt * 16 + lane16];

    float4v acc[4][4];
    #pragma unroll
    for (int a = 0; a < 4; ++a)
        #pragma unroll
        for (int b = 0; b < 4; ++b)
            acc[a][b] = (float4v){0.f, 0.f, 0.f, 0.f};

    __syncthreads();                           // drains gll16s (and A loads)

    #pragma unroll
    for (int cs = 0; cs < 4; ++cs) {
        long2v bv[4];
        #pragma unroll
        for (int jt = 0; jt < 4; ++jt)
            bv[jt] = *(const long2v*)(Bs8
                     + (((((wj * 4 + jt) << 2) | cs) << 10)) + lane * 16);
        #pragma unroll
        for (int h = 0; h < 2; ++h)
            #pragma unroll
            for (int it = 0; it < 4; ++it)
                #pragma unroll
                for (int jt = 0; jt < 4; ++jt)
                    acc[it][jt] = __builtin_amdgcn_mfma_f32_16x16x32_fp8_fp8(
                        av[it][cs][h], bv[jt][h], acc[it][jt], 0, 0, 0);
    }

    // epilogue (R21): unmasked per-column stats; acc = 64*sim.
    // e = exp(acc/32) = native_exp2(acc * log2e/32); tt accumulates RAW acc.
    float ex[4] = {0,0,0,0}, pe[4] = {0,0,0,0};
    float tt[4] = {0,0,0,0}, pc[4] = {0,0,0,0};
    #pragma unroll
    for (int it = 0; it < 4; ++it) {
        #pragma unroll
        for (int jt = 0; jt < 4; ++jt) {
            #pragma unroll
            for (int r = 0; r < 4; ++r) {
                float a = acc[it][jt][r];
                float e = __builtin_amdgcn_exp2f(a * 0.04508422f); // log2e/32
                float m = (labi[it * 4 + r] == labj[jt]) ? 1.0f : 0.0f;
                ex[jt] += e;
                pe[jt] = fmaf(m, e, pe[jt]);
                tt[jt] = fmaf(m, a, tt[jt]);            // raw; scaled at store
                pc[jt] += m;
            }
        }
    }
    int i64 = bi * 2 + wi;                     // this wave's 64-row chunk
    #pragma unroll
    for (int jt = 0; jt < 4; ++jt) {
        float v0 = ex[jt], v1 = pe[jt], v2 = tt[jt], v3 = pc[jt];
        v0 += __shfl_xor(v0, 16); v0 += __shfl_xor(v0, 32);
        v1 += __shfl_xor(v1, 16); v1 += __shfl_xor(v1, 32);
        v2 += __shfl_xor(v2, 16); v2 += __shfl_xor(v2, 32);
        v3 += __shfl_xor(v3, 16); v3 += __shfl_xor(v3, 32);
        if (quad == 0) {
            int col = jbase + jt * 16 + lane16;
            part[((0 * 64 + i64) << 12) + col] = v0;
            part[((1 * 64 + i64) << 12) + col] = v1;
            part[((2 * 64 + i64) << 12) + col] = v2 * 0.03125f;  // -> t2 sum
            part[((3 * 64 + i64) << 12) + col] = v3;
        }
    }
}

// ---------------------------------------------------------------------------
// K3: slice-parallel rowreduce, coalesced mapping (R16). Grid 128 x 256.
// Diag correction (validated R19/R20): sums include the diag elem; quantized
// e_ii cancels exactly in n = exsum - pexp; pos-side uses pe - exp(2),
// tt - 2, pc - 1 (error ~1e-3 << threshold).
__global__ void rowreduce_kernel(const float* __restrict__ part,
                                 float* __restrict__ acc,
                                 float* __restrict__ out) {
    int t = threadIdx.x;
    int rl = t & 31, sl = t >> 5;              // 8 slices x 32 rows
    int row = blockIdx.x * 32 + rl;
    float s[4];
    #pragma unroll
    for (int st = 0; st < 4; ++st) {
        float v = 0.f;
        #pragma unroll
        for (int c = 0; c < 8; ++c)
            v += part[((st * 64 + (sl * 8 + c)) << 12) + row];
        s[st] = v;
    }
    // combine the wave's two slices (lane ^ 32 = same row, other slice)
    #pragma unroll
    for (int st = 0; st < 4; ++st) s[st] += __shfl_xor(s[st], 32);
    __shared__ float sred[4][4][32];           // [wave][stat][row]
    int wave = t >> 6, lane = t & 63;
    if (lane < 32) {
        #pragma unroll
        for (int st = 0; st < 4; ++st) sred[wave][st][lane] = s[st];
    }
    __syncthreads();
    float lsum = 0.f, pcm = 0.f;
    if (t < 32) {
        float tot[4];
        #pragma unroll
        for (int st = 0; st < 4; ++st)
            tot[st] = sred[0][st][t] + sred[1][st][t]
                    + sred[2][st][t] + sred[3][st][t];
        float n   = tot[0] - tot[1];           // diag e_ii cancels exactly
        float pec = tot[1] - 7.3890560989f;    // pe  - exp(2)
        float ttc = tot[2] - 2.0f;             // tt  - 2
        float pcc = tot[3] - 1.0f;             // cnt - 1 (diag)
        if (pcc > 0.5f) {
            lsum = pcc * logf(n) + pec / n - ttc;
            pcm  = pcc;
        }
    }
    #pragma unroll
    for (int m = 1; m < 32; m <<= 1) {         // lanes 0..31 of wave 0
        lsum += __shfl_xor(lsum, m);
        pcm  += __shfl_xor(pcm,  m);
    }
    if (t == 0) {
        atomicAdd(&acc[0], lsum);
        atomicAdd(&acc[1], pcm);
        __threadfence();
        int ticket = atomicAdd((int*)(acc + 2), 1);
        if (ticket == 127) {
            float ls = atomicAdd(&acc[0], 0.0f);
            float cs = atomicAdd(&acc[1], 0.0f);
            out[0] = ls / cs;
        }
    }
}

// ---------------------------------------------------------------------------
extern "C" void kernel_launch(void* const* d_in, const int* in_sizes, int n_in,
                              void* d_out, int out_size, void* d_ws, size_t ws_size,
                              hipStream_t stream) {
    const float* emb    = (const float*)d_in[0];
    const int*   labels = (const int*)d_in[1];
    float* out = (float*)d_out;
    char*  ws  = (char*)d_ws;

    unsigned char* pk8  = (unsigned char*)(ws + PK_OFF);
    float*         part = (float*)(ws + PART_OFF);
    float*         acc  = (float*)(ws + ACC_OFF);

    normalize_kernel<<<N_ROWS / 16, 256, 0, stream>>>(emb, pk8, acc);
    negsum_kernel<<<1024, 256, 0, stream>>>(pk8, labels, part);
    rowreduce_kernel<<<128, 256, 0, stream>>>(part, acc, out);
}